// Round 5
// baseline (395.002 us; speedup 1.0000x reference)
//
#include <hip/hip_runtime.h>
#include <math.h>

#define TT 8192
#define HH 768
#define II 3072
#define EE 8
#define MAXT 72

typedef short bf16x8 __attribute__((ext_vector_type(8)));
typedef float f32x4 __attribute__((ext_vector_type(4)));

__device__ __forceinline__ ushort f2b(float f) {
    union { float f; unsigned int i; } x; x.f = f;
    unsigned int r = x.i + 0x7fffu + ((x.i >> 16) & 1u);
    return (ushort)(r >> 16);
}
__device__ __forceinline__ float b2f(ushort u) {
    union { unsigned int i; float f; } x; x.i = ((unsigned int)u) << 16; return x.f;
}

__device__ __forceinline__ void glds16(const ushort* g, ushort* l) {
    __builtin_amdgcn_global_load_lds(
        (const __attribute__((address_space(1))) void*)g,
        (__attribute__((address_space(3))) void*)l, 16, 0, 0);
}

// A&S 7.1.26 erf (max abs err 1.5e-7) -> exact-GELU
__device__ __forceinline__ float fast_gelu(float v) {
    float x = v * 0.70710678118654752f;
    float ax = fabsf(x);
    float t = __builtin_amdgcn_rcpf(__builtin_fmaf(0.3275911f, ax, 1.0f));
    float p = __builtin_fmaf(t, 1.061405429f, -1.453152027f);
    p = __builtin_fmaf(t, p, 1.421413741f);
    p = __builtin_fmaf(t, p, -0.284496736f);
    p = __builtin_fmaf(t, p, 0.254829592f);
    p = p * t;
    float e = __expf(-ax * ax);
    float erf_abs = 1.0f - p * e;
    float er = (x < 0.0f) ? -erf_abs : erf_abs;
    return 0.5f * v * (1.0f + er);
}

// ---------------- permutation + tile map ----------------
__global__ __launch_bounds__(1024) void build_perm(const int* __restrict__ eids,
                                                   int* __restrict__ tok_sorted,
                                                   int* __restrict__ off,
                                                   int* __restrict__ meta,
                                                   int write_tiles) {
    __shared__ int cnt[EE], cur[EE], offs[EE + 1];
    int tid = threadIdx.x;
    if (tid < EE) cnt[tid] = 0;
    __syncthreads();
    for (int t = tid; t < TT; t += 1024) atomicAdd(&cnt[eids[t]], 1);
    __syncthreads();
    if (tid == 0) {
        int s = 0;
        for (int e = 0; e < EE; e++) { offs[e] = s; s += cnt[e]; }
        offs[EE] = s;
        if (write_tiles) {
            int nt = 0;
            for (int e = 0; e < EE; e++) {
                int c = offs[e + 1] - offs[e];
                for (int m0 = 0; m0 < c; m0 += 128) {
                    meta[16 + nt] = e;
                    meta[96 + nt] = offs[e] + m0;
                    meta[176 + nt] = (c - m0 < 128) ? (c - m0) : 128;
                    nt++;
                }
            }
            meta[0] = nt;
        }
    }
    __syncthreads();
    if (tid < EE) cur[tid] = offs[tid];
    if (tid < EE + 1) off[tid] = offs[tid];
    __syncthreads();
    for (int t = tid; t < TT; t += 1024) {
        int p = atomicAdd(&cur[eids[t]], 1);
        tok_sorted[p] = t;
    }
}

// ---------------- gather + f32->bf16 convert of X into sorted order ----------------
__global__ __launch_bounds__(192) void cvtX(const float* __restrict__ X,
                                            const int* __restrict__ tok_sorted,
                                            ushort* __restrict__ Xs) {
    int r = blockIdx.x;
    int t = tok_sorted[r];
    int h = threadIdx.x * 4;
    float4 v = *(const float4*)(X + (size_t)t * HH + h);
    ushort4 o;
    o.x = f2b(v.x); o.y = f2b(v.y); o.z = f2b(v.z); o.w = f2b(v.w);
    *(ushort4*)(Xs + (size_t)r * HH + h) = o;
}

// ---------------- transpose + convert both weights: f32 [R][C] -> bf16 [C][R] ----------------
// Coalesced on both sides: reads 256B-contiguous per row-group; writes 128B-contiguous
// runs along R per dst column (8 lanes cover one column's 64 elements).
__global__ __launch_bounds__(256) void tcvt2(const float* __restrict__ W1,
                                             const float* __restrict__ W2,
                                             ushort* __restrict__ W1t,
                                             ushort* __restrict__ W2t) {
    int which = blockIdx.z;
    int R = which ? II : HH;
    int C = which ? HH : II;
    const float* src = (which ? W2 : W1) + (size_t)blockIdx.y * R * C;
    ushort* dst = (which ? W2t : W1t) + (size_t)blockIdx.y * R * C;
    int ctiles = C >> 6;
    int c0 = (blockIdx.x % ctiles) * 64, r0 = (blockIdx.x / ctiles) * 64;
    __shared__ float T[64][65];
    int tid = threadIdx.x;
    int rr = tid >> 4;          // 0..15
    int cc = (tid & 15) * 4;    // 0..60
#pragma unroll
    for (int i = 0; i < 4; i++) {
        float4 v = *(const float4*)(src + (size_t)(r0 + i * 16 + rr) * C + c0 + cc);
        T[i * 16 + rr][cc] = v.x; T[i * 16 + rr][cc + 1] = v.y;
        T[i * 16 + rr][cc + 2] = v.z; T[i * 16 + rr][cc + 3] = v.w;
    }
    __syncthreads();
    int tc = tid >> 3, tr = tid & 7;   // tc 0..31 (c), tr 0..7 (r-chunk of 8)
#pragma unroll
    for (int pass = 0; pass < 2; pass++) {
        int c = pass * 32 + tc;
        union { ushort u[8]; uint4 v; } p;
#pragma unroll
        for (int j = 0; j < 8; j++) p.u[j] = f2b(T[tr * 8 + j][c]);
        *(uint4*)(dst + (size_t)(c0 + c) * R + r0 + tr * 8) = p.v;
    }
}

// ---------------- grouped GEMM: out = act(A[kb:kb+KS] @ B^T[kb:kb+KS] + bias) ----------------
// BK=32, LDS double-buffer, ONE barrier per iter: stage k+1's DMA before computing k,
// so the compiler's vmcnt(0) drain at the barrier lands after the compute overlap.
// XOR-swizzled LDS (0 conflicts, verified R3->R4). 128x128 tile, bias only when kb==0.
template<int KT, int KS, int NT, bool GELU>
__global__ __launch_bounds__(256, 3) void gemm_k(const ushort* __restrict__ A,
                                                 const ushort* __restrict__ B,
                                                 const float* __restrict__ bias,
                                                 const int* __restrict__ meta,
                                                 ushort* __restrict__ outp) {
    int bx = blockIdx.x;
    if (bx >= meta[0]) return;
    int e = meta[16 + bx];
    int start = meta[96 + bx];
    int rows = meta[176 + bx];
    int n0 = blockIdx.y * 128;
    int kb = blockIdx.z * KS;
    ushort* out = outp + (size_t)blockIdx.z * TT * NT;

    const ushort* Be = B + (size_t)e * NT * KT;
    const float* be = bias + (size_t)e * NT;

    __shared__ ushort As0[4096], Bs0[4096], As1[4096], Bs1[4096];

    int tid = threadIdx.x;
    int lane = tid & 63, m = lane & 15, quad = lane >> 4;
    int wv = tid >> 6, wm = wv & 1, wn = wv >> 1;

    // staging: slot s=(row r=s>>2, chunk c=s&3) holds src kchunk c ^ ((r>>1)&3)
    int rA = tid >> 2;
    int kcs = (tid & 3) ^ ((tid >> 3) & 3);
    const ushort* ga0 = A + (size_t)(start + rA) * KT + kb + kcs * 8;
    const ushort* ga1 = ga0 + (size_t)64 * KT;
    const ushort* gb0 = Be + (size_t)(n0 + rA) * KT + kb + kcs * 8;
    const ushort* gb1 = gb0 + (size_t)64 * KT;

    f32x4 acc[4][4] = {};

    int qx = quad ^ ((m >> 1) & 3);
    int foA = (wm * 64 + m) * 32 + qx * 8;
    int foB = (wn * 64 + m) * 32 + qx * 8;

    constexpr int NIT = KS / 32;
    // prologue: stage buf0 (k=0 of this block's span)
    glds16(ga0, As0 + wv * 512);
    glds16(ga1, As0 + 2048 + wv * 512);
    glds16(gb0, Bs0 + wv * 512);
    glds16(gb1, Bs0 + 2048 + wv * 512);

    for (int it = 0; it < NIT; ++it) {
        __syncthreads();   // drains prev DMA (buf[it&1] ready) + prev iter's ds_reads
        ga0 += 32; ga1 += 32; gb0 += 32; gb1 += 32;
        if (it + 1 < NIT) {
            if (it & 1) {
                glds16(ga0, As0 + wv * 512);
                glds16(ga1, As0 + 2048 + wv * 512);
                glds16(gb0, Bs0 + wv * 512);
                glds16(gb1, Bs0 + 2048 + wv * 512);
            } else {
                glds16(ga0, As1 + wv * 512);
                glds16(ga1, As1 + 2048 + wv * 512);
                glds16(gb0, Bs1 + wv * 512);
                glds16(gb1, Bs1 + 2048 + wv * 512);
            }
        }
        const ushort* as = (it & 1) ? As1 : As0;
        const ushort* bs = (it & 1) ? Bs1 : Bs0;
        bf16x8 a[4], b[4];
#pragma unroll
        for (int i = 0; i < 4; i++) a[i] = *(const bf16x8*)(as + foA + i * 16 * 32);
#pragma unroll
        for (int j = 0; j < 4; j++) b[j] = *(const bf16x8*)(bs + foB + j * 16 * 32);
#pragma unroll
        for (int i = 0; i < 4; i++)
#pragma unroll
            for (int j = 0; j < 4; j++)
                acc[i][j] = __builtin_amdgcn_mfma_f32_16x16x32_bf16(a[i], b[j], acc[i][j], 0, 0, 0);
    }

    float bv[4];
#pragma unroll
    for (int j = 0; j < 4; j++) bv[j] = (kb == 0) ? be[n0 + wn * 64 + j * 16 + m] : 0.0f;

#pragma unroll
    for (int i = 0; i < 4; i++) {
#pragma unroll
        for (int r = 0; r < 4; r++) {
            int row = wm * 64 + i * 16 + quad * 4 + r;
            if (row < rows) {
#pragma unroll
                for (int j = 0; j < 4; j++) {
                    int col = n0 + wn * 64 + j * 16 + m;
                    float v = acc[i][j][r] + bv[j];
                    if (GELU) v = fast_gelu(v);
                    out[(size_t)(start + row) * NT + col] = f2b(v);
                }
            }
        }
    }
}

// ---------------- split-K reduce + residual + LayerNorm + scatter ----------------
__global__ __launch_bounds__(256) void ln2_kernel(const ushort* __restrict__ sel0,
                                                  const ushort* __restrict__ sel1,
                                                  const float* __restrict__ X,
                                                  const float* __restrict__ gamma,
                                                  const float* __restrict__ beta,
                                                  const int* __restrict__ tok_sorted,
                                                  float* __restrict__ out) {
    int r = blockIdx.x;
    int tok = tok_sorted[r];
    int tid = threadIdx.x;

    float v[3];
    float s = 0.f, s2 = 0.f;
#pragma unroll
    for (int j = 0; j < 3; j++) {
        int h = tid + j * 256;
        float t = b2f(sel0[(size_t)r * HH + h]) + b2f(sel1[(size_t)r * HH + h])
                + X[(size_t)tok * HH + h];
        v[j] = t; s += t; s2 += t * t;
    }
#pragma unroll
    for (int o = 32; o > 0; o >>= 1) {
        s += __shfl_down(s, o);
        s2 += __shfl_down(s2, o);
    }
    __shared__ float ws1[4], ws2[4];
    int lane = tid & 63, w = tid >> 6;
    if (lane == 0) { ws1[w] = s; ws2[w] = s2; }
    __syncthreads();
    __shared__ float mu_s, rs_s;
    if (tid == 0) {
        float a = 0.f, b = 0.f;
        for (int i = 0; i < 4; i++) { a += ws1[i]; b += ws2[i]; }
        float mu = a / (float)HH;
        float var = b / (float)HH - mu * mu;
        mu_s = mu;
        rs_s = rsqrtf(var + 1e-12f);
    }
    __syncthreads();
    float mu = mu_s, rs = rs_s;
#pragma unroll
    for (int j = 0; j < 3; j++) {
        int h = tid + j * 256;
        float o = (v[j] - mu) * rs * gamma[h] + beta[h];
        out[(size_t)tok * HH + h] = o;
    }
}

// ---------------- fallback LN (f32 sel + residual) ----------------
__global__ __launch_bounds__(256) void ln_kernel(const float* __restrict__ sel,
                                                 const float* __restrict__ X,
                                                 const float* __restrict__ gamma,
                                                 const float* __restrict__ beta,
                                                 const int* __restrict__ tok_sorted,
                                                 float* __restrict__ out) {
    int r = blockIdx.x;
    int tok = tok_sorted[r];
    int tid = threadIdx.x;
    float v[3];
    float s = 0.f, s2 = 0.f;
#pragma unroll
    for (int j = 0; j < 3; j++) {
        int h = tid + j * 256;
        float t = sel[(size_t)r * HH + h] + X[(size_t)tok * HH + h];
        v[j] = t; s += t; s2 += t * t;
    }
#pragma unroll
    for (int o = 32; o > 0; o >>= 1) {
        s += __shfl_down(s, o);
        s2 += __shfl_down(s2, o);
    }
    __shared__ float ws1[4], ws2[4];
    int lane = tid & 63, w = tid >> 6;
    if (lane == 0) { ws1[w] = s; ws2[w] = s2; }
    __syncthreads();
    __shared__ float mu_s, rs_s;
    if (tid == 0) {
        float a = 0.f, b = 0.f;
        for (int i = 0; i < 4; i++) { a += ws1[i]; b += ws2[i]; }
        float mu = a / (float)HH;
        float var = b / (float)HH - mu * mu;
        mu_s = mu;
        rs_s = rsqrtf(var + 1e-12f);
    }
    __syncthreads();
    float mu = mu_s, rs = rs_s;
#pragma unroll
    for (int j = 0; j < 3; j++) {
        int h = tid + j * 256;
        float o = (v[j] - mu) * rs * gamma[h] + beta[h];
        out[(size_t)tok * HH + h] = o;
    }
}

// ================= fallback (small ws) kernels =================
__global__ __launch_bounds__(256) void gemm1_s(const float* __restrict__ X,
                                               const float* __restrict__ W1,
                                               const float* __restrict__ B1,
                                               const int* __restrict__ tok_sorted,
                                               const int* __restrict__ off,
                                               ushort* __restrict__ inter) {
    int slot = blockIdx.x;
    int e = slot >> 7, tile = slot & 127;
    int start = off[e] + (tile << 6);
    int end = off[e + 1];
    if (start >= end) return;
    int rows = end - start; if (rows > 64) rows = 64;
    int n0 = blockIdx.y << 6;
    const float* W1e = W1 + (size_t)e * HH * II;
    __shared__ ushort As[64 * 32];
    __shared__ ushort Bt[64 * 32];
    int tid = threadIdx.x;
    int w = tid >> 6, lane = tid & 63, m = lane & 15, quad = lane >> 4;
    int rrA = tid >> 2, c8A = tid & 3;
    int tokA = tok_sorted[start + (rrA < rows ? rrA : 0)];
    const float* gA = X + (size_t)tokA * HH + c8A * 8;
    int kB = tid >> 3, n8 = tid & 7;
    const float* gB = W1e + (size_t)kB * II + n0 + n8 * 8;
    f32x4 acc[4] = {};
    for (int k0 = 0; k0 < HH; k0 += 32) {
        float4 a0 = *(const float4*)(gA + k0);
        float4 a1 = *(const float4*)(gA + k0 + 4);
        float4 b0 = *(const float4*)(gB + (size_t)k0 * II);
        float4 b1 = *(const float4*)(gB + (size_t)k0 * II + 4);
        __syncthreads();
        union { ushort u[8]; uint4 v; } ta;
        ta.u[0] = f2b(a0.x); ta.u[1] = f2b(a0.y); ta.u[2] = f2b(a0.z); ta.u[3] = f2b(a0.w);
        ta.u[4] = f2b(a1.x); ta.u[5] = f2b(a1.y); ta.u[6] = f2b(a1.z); ta.u[7] = f2b(a1.w);
        *(uint4*)&As[rrA * 32 + c8A * 8] = ta.v;
        float bb[8] = {b0.x, b0.y, b0.z, b0.w, b1.x, b1.y, b1.z, b1.w};
#pragma unroll
        for (int j = 0; j < 8; j++) Bt[(n8 * 8 + j) * 32 + kB] = f2b(bb[j]);
        __syncthreads();
        bf16x8 a = *(const bf16x8*)&As[(w * 16 + m) * 32 + quad * 8];
#pragma unroll
        for (int nb = 0; nb < 4; nb++) {
            bf16x8 b = *(const bf16x8*)&Bt[(nb * 16 + m) * 32 + quad * 8];
            acc[nb] = __builtin_amdgcn_mfma_f32_16x16x32_bf16(a, b, acc[nb], 0, 0, 0);
        }
    }
    const float* b1e = B1 + (size_t)e * II;
#pragma unroll
    for (int nb = 0; nb < 4; nb++) {
        int col = n0 + nb * 16 + m;
        float bias = b1e[col];
#pragma unroll
        for (int r = 0; r < 4; r++) {
            int row = w * 16 + quad * 4 + r;
            if (row < rows) {
                float v = acc[nb][r] + bias;
                inter[(size_t)(start + row) * II + col] = f2b(fast_gelu(v));
            }
        }
    }
}

__global__ __launch_bounds__(256) void gemm2_s(const ushort* __restrict__ inter,
                                               const float* __restrict__ W2,
                                               const float* __restrict__ B2,
                                               const int* __restrict__ off,
                                               float* __restrict__ sel) {
    int slot = blockIdx.x;
    int e = slot >> 7, tile = slot & 127;
    int start = off[e] + (tile << 6);
    int end = off[e + 1];
    if (start >= end) return;
    int rows = end - start; if (rows > 64) rows = 64;
    int n0 = blockIdx.y << 6;
    const float* W2e = W2 + (size_t)e * II * HH;
    __shared__ ushort As[64 * 32];
    __shared__ ushort Bt[64 * 32];
    int tid = threadIdx.x;
    int w = tid >> 6, lane = tid & 63, m = lane & 15, quad = lane >> 4;
    int rrA = tid >> 2, c8A = tid & 3;
    int rA = start + rrA; if (rA > TT - 1) rA = TT - 1;
    const ushort* gA = inter + (size_t)rA * II + c8A * 8;
    int kB = tid >> 3, n8 = tid & 7;
    const float* gB = W2e + (size_t)kB * HH + n0 + n8 * 8;
    f32x4 acc[4] = {};
    for (int k0 = 0; k0 < II; k0 += 32) {
        uint4 av = *(const uint4*)(gA + k0);
        float4 b0 = *(const float4*)(gB + (size_t)k0 * HH);
        float4 b1 = *(const float4*)(gB + (size_t)k0 * HH + 4);
        __syncthreads();
        *(uint4*)&As[rrA * 32 + c8A * 8] = av;
        float bb[8] = {b0.x, b0.y, b0.z, b0.w, b1.x, b1.y, b1.z, b1.w};
#pragma unroll
        for (int j = 0; j < 8; j++) Bt[(n8 * 8 + j) * 32 + kB] = f2b(bb[j]);
        __syncthreads();
        bf16x8 a = *(const bf16x8*)&As[(w * 16 + m) * 32 + quad * 8];
#pragma unroll
        for (int nb = 0; nb < 4; nb++) {
            bf16x8 b = *(const bf16x8*)&Bt[(nb * 16 + m) * 32 + quad * 8];
            acc[nb] = __builtin_amdgcn_mfma_f32_16x16x32_bf16(a, b, acc[nb], 0, 0, 0);
        }
    }
    const float* b2e = B2 + (size_t)e * HH;
#pragma unroll
    for (int nb = 0; nb < 4; nb++) {
        int col = n0 + nb * 16 + m;
        float bias = b2e[col];
#pragma unroll
        for (int r = 0; r < 4; r++) {
            int row = w * 16 + quad * 4 + r;
            if (row < rows) sel[(size_t)(start + row) * HH + col] = acc[nb][r] + bias;
        }
    }
}

extern "C" void kernel_launch(void* const* d_in, const int* in_sizes, int n_in,
                              void* d_out, int out_size, void* d_ws, size_t ws_size,
                              hipStream_t stream) {
    const float* X  = (const float*)d_in[0];
    const float* W1 = (const float*)d_in[1];
    const float* B1 = (const float*)d_in[2];
    const float* W2 = (const float*)d_in[3];
    const float* B2 = (const float*)d_in[4];
    const float* G  = (const float*)d_in[5];
    const float* Bt = (const float*)d_in[6];
    const int* eids = (const int*)d_in[7];
    float* out = (float*)d_out;
    char* ws = (char*)d_ws;

    const size_t XS_OFF    = 34816;
    const size_t XS_SZ     = (size_t)2 * (TT + 128) * HH;
    const size_t W1T_OFF   = XS_OFF + XS_SZ;
    const size_t W1T_SZ    = (size_t)2 * EE * HH * II;
    const size_t W2T_OFF   = W1T_OFF + W1T_SZ;
    const size_t INTER_OFF = W2T_OFF + W1T_SZ;
    const size_t INTER_SZ  = (size_t)2 * (TT + 128) * II;
    const size_t SEL_OFF   = INTER_OFF + INTER_SZ;
    const size_t SEL_SZ    = (size_t)4 * TT * HH;      // holds 2 bf16 halves of [T][H]
    const size_t NEED      = SEL_OFF + SEL_SZ;

    if (ws_size >= NEED) {
        int* off = (int*)ws;
        int* meta = (int*)(ws + 64);
        int* tok = (int*)(ws + 2048);
        ushort* Xs = (ushort*)(ws + XS_OFF);
        ushort* W1t = (ushort*)(ws + W1T_OFF);
        ushort* W2t = (ushort*)(ws + W2T_OFF);
        ushort* inter = (ushort*)(ws + INTER_OFF);
        ushort* sel01 = (ushort*)(ws + SEL_OFF);        // [2][T][H] bf16

        build_perm<<<1, 1024, 0, stream>>>(eids, tok, off, meta, 1);
        cvtX<<<TT, 192, 0, stream>>>(X, tok, Xs);
        tcvt2<<<dim3(576, EE, 2), 256, 0, stream>>>(W1, W2, W1t, W2t);
        gemm_k<HH, HH, II, true><<<dim3(MAXT, II / 128, 1), 256, 0, stream>>>(Xs, W1t, B1, meta, inter);
        gemm_k<II, II / 2, HH, false><<<dim3(MAXT, HH / 128, 2), 256, 0, stream>>>(inter, W2t, B2, meta, sel01);
        ln2_kernel<<<TT, 256, 0, stream>>>(sel01, sel01 + (size_t)TT * HH, X, G, Bt, tok, out);
    } else {
        int* off = (int*)ws;
        int* tok = (int*)(ws + 64);
        ushort* inter = (ushort*)(ws + 64 + 4 * TT);
        float* sel = (float*)(ws + 64 + 4 * TT + (size_t)2 * TT * II);
        build_perm<<<1, 1024, 0, stream>>>(eids, tok, off, off, 0);
        gemm1_s<<<dim3(EE * 128, II / 64), 256, 0, stream>>>(X, W1, B1, tok, off, inter);
        gemm2_s<<<dim3(EE * 128, HH / 64), 256, 0, stream>>>(inter, W2, B2, off, sel);
        ln_kernel<<<TT, 256, 0, stream>>>(sel, X, G, Bt, tok, out);
    }
}